// Round 3
// baseline (524.911 us; speedup 1.0000x reference)
//
#include <hip/hip_runtime.h>
#include <hip/hip_bf16.h>

typedef __bf16 bf16;
typedef __bf16 bf16x4 __attribute__((ext_vector_type(4)));
typedef __bf16 bf16x8 __attribute__((ext_vector_type(8)));
typedef float  f32x4  __attribute__((ext_vector_type(4)));

#define SEQ  2048
#define HID  4096
#define QKVN 6144   // 4096 Q + 1024 K + 1024 V

__device__ __forceinline__ void gload_lds16(const void* g, void* l) {
  __builtin_amdgcn_global_load_lds(
      (const __attribute__((address_space(1))) void*)g,
      (__attribute__((address_space(3))) void*)l, 16, 0, 0);
}

// ---------------- cast f32 -> bf16 (vectorized) ----------------
__global__ __launch_bounds__(256) void cast_f32_bf16(const float* __restrict__ in,
                                                     bf16* __restrict__ out, int n) {
  int i = (blockIdx.x * 256 + threadIdx.x) * 4;
  int stride = gridDim.x * 256 * 4;
  for (; i < n; i += stride) {
    float4 v = *(const float4*)(in + i);
    bf16x4 o;
    o[0] = (bf16)v.x; o[1] = (bf16)v.y; o[2] = (bf16)v.z; o[3] = (bf16)v.w;
    *(bf16x4*)(out + i) = o;
  }
}

// ---------------- tiled transpose + cast: W[4096][N] f32 -> Wt[roff+N][4096] bf16 ----------------
__global__ __launch_bounds__(256) void transpose_cast(const float* __restrict__ W,
                                                      bf16* __restrict__ Wt,
                                                      int N, int roff) {
  __shared__ float tile[32][33];
  int k0 = blockIdx.y * 32;
  int n0 = blockIdx.x * 32;
  int t = threadIdx.x;
  int r = t >> 5, c = t & 31;
#pragma unroll
  for (int p = 0; p < 4; ++p)
    tile[r + p * 8][c] = W[(size_t)(k0 + r + p * 8) * N + n0 + c];
  __syncthreads();
#pragma unroll
  for (int p = 0; p < 4; ++p)
    Wt[(size_t)(roff + n0 + r + p * 8) * 4096 + k0 + c] = (bf16)tile[c][r + p * 8];
}

// ---------------- transpose V out of QKV into global: Vt_g[g][d][s] ----------------
__global__ __launch_bounds__(256) void transpose_v(const bf16* __restrict__ QKV,
                                                   bf16* __restrict__ Vt_g) {
  __shared__ bf16 tile[32][33];
  int s0 = blockIdx.x * 32;          // seq tile
  int d0 = blockIdx.y * 32;          // head-dim tile
  int g  = blockIdx.z;               // kv head
  int t = threadIdx.x;
  int r = t >> 5, c = t & 31;
#pragma unroll
  for (int p = 0; p < 4; ++p)
    tile[r + p * 8][c] = QKV[(size_t)(s0 + r + p * 8) * QKVN + 5120 + g * 128 + d0 + c];
  __syncthreads();
#pragma unroll
  for (int p = 0; p < 4; ++p)
    Vt_g[(size_t)(g * 128 + d0 + r + p * 8) * SEQ + s0 + c] = tile[c][r + p * 8];
}

// ================= 256x256 8-phase GEMM (m201-style template, K=4096 fixed) =================
// A[M][4096] @ Bt[N][4096]^T -> C[M][ldc]. 512 thr = 8 waves (2M x 4N), per-wave 128x64 out.
// BK=64, 2 K-tiles/iter, 8 phases/iter, double-buffered 128KiB LDS, row&7 16B-slot XOR swizzle,
// counted vmcnt(4) at phases 4/8, setprio around MFMA clusters.
#define RD_A(dst, base, moff) \
  _Pragma("unroll") for (int m_ = 0; m_ < 4; ++m_) \
  _Pragma("unroll") for (int kk_ = 0; kk_ < 2; ++kk_) \
    dst[m_][kk_] = *(const bf16x8*)((base) + (wr * 128 + (moff + m_) * 16 + l15) * 128 + \
                                    (((kk_ * 64) + l4 * 16) ^ swz));
#define RD_B(dst, base, noff) \
  _Pragma("unroll") for (int n_ = 0; n_ < 2; ++n_) \
  _Pragma("unroll") for (int kk_ = 0; kk_ < 2; ++kk_) \
    dst[n_][kk_] = *(const bf16x8*)((base) + (wc * 64 + (noff + n_) * 16 + l15) * 128 + \
                                    (((kk_ * 64) + l4 * 16) ^ swz));
#define MM(af, bf_, moff, noff) \
  _Pragma("unroll") for (int m_ = 0; m_ < 4; ++m_) \
  _Pragma("unroll") for (int n_ = 0; n_ < 2; ++n_) \
  _Pragma("unroll") for (int kk_ = 0; kk_ < 2; ++kk_) \
    acc[moff + m_][noff + n_] = __builtin_amdgcn_mfma_f32_16x16x32_bf16( \
        af[m_][kk_], bf_[n_][kk_], acc[moff + m_][noff + n_], 0, 0, 0);
#define PH_SYNC_MFMA_BEGIN \
  asm volatile("" ::: "memory"); __builtin_amdgcn_s_barrier(); \
  asm volatile("s_waitcnt lgkmcnt(0)" ::: "memory"); \
  __builtin_amdgcn_s_setprio(1);
#define PH_END \
  __builtin_amdgcn_s_setprio(0); \
  asm volatile("" ::: "memory"); __builtin_amdgcn_s_barrier(); asm volatile("" ::: "memory");

template <typename OUT_T>
__global__ __launch_bounds__(512, 2) void gemm256(const bf16* __restrict__ A,
                                                  const bf16* __restrict__ Bt,
                                                  OUT_T* __restrict__ C,
                                                  int NB, int ldc) {
  __shared__ __align__(16) char lds[131072];
  const int bid = blockIdx.x, nwg = gridDim.x;
  const int cpx = nwg >> 3;                       // nwg % 8 == 0 (192 / 128)
  const int wid = (bid & 7) * cpx + (bid >> 3);   // XCD-aware bijective remap
  const int mb = wid / NB, nb = wid % NB;
  const int m0 = mb << 8, n0 = nb << 8;
  const int tid = threadIdx.x;
  const int w = tid >> 6, lane = tid & 63;
  const int wr = w >> 2, wc = w & 3;
  const int l15 = lane & 15, l4 = lane >> 4;
  const int swz = (l15 & 7) << 4;

  char* const A0c = lds;
  char* const B0c = lds + 32768;
  char* const A1c = lds + 65536;
  char* const B1c = lds + 98304;

  // stage one 128-row x 64-col half-tile (16KB): linear LDS dest, inverse-swizzled global src
  auto stage = [&](const bf16* __restrict__ g, int grow0, int k0, char* dst) {
#pragma unroll
    for (int j = 0; j < 2; ++j) {
      int c = tid + (j << 9);
      int row = c >> 3, slot = c & 7;
      gload_lds16((const char*)(g + ((size_t)(grow0 + row) << 12) + k0) +
                      ((slot ^ (row & 7)) << 4),
                  dst + c * 16);
    }
  };

  f32x4 acc[8][4] = {};
  bf16x8 a0[4][2], a1[4][2], b0[2][2], b1[2][2];

  // ---- prologue: T0 (4 halves -> buf0) + T1 A-halves (-> buf1); vmcnt(4) leaves T1.A in flight
  stage(A,  m0,        0,  A0c);
  stage(A,  m0 + 128,  0,  A0c + 16384);
  stage(Bt, n0,        0,  B0c);
  stage(Bt, n0 + 128,  0,  B0c + 16384);
  stage(A,  m0,        64, A1c);
  stage(A,  m0 + 128,  64, A1c + 16384);
  asm volatile("s_waitcnt vmcnt(4)" ::: "memory");
  __builtin_amdgcn_s_barrier();

  for (int it = 0; it < 32; ++it) {
    const int k1 = (2 * it + 1) << 6;
    const int k2 = (2 * it + 2) << 6;
    const int k3 = (2 * it + 3) << 6;
    const bool more = (it < 31);
    // P1: reads buf0{A03,B01}; stage buf1.Bh0 (tile 2it+1)
    RD_A(a0, A0c, 0); RD_B(b0, B0c, 0);
    stage(Bt, n0, k1, B1c);
    PH_SYNC_MFMA_BEGIN; MM(a0, b0, 0, 0); PH_END;
    // P2: reads buf0{A47,B23}; stage buf1.Bh1
    RD_A(a1, A0c, 4); RD_B(b1, B0c, 2);
    stage(Bt, n0 + 128, k1, B1c + 16384);
    PH_SYNC_MFMA_BEGIN; MM(a0, b1, 0, 2); PH_END;
    // P3: buf0 fully consumed -> refill buf0.Ah0 (tile 2it+2)
    if (more) stage(A, m0, k2, A0c);
    PH_SYNC_MFMA_BEGIN; MM(a1, b0, 4, 0); PH_END;
    // P4: refill buf0.Ah1; counted vmcnt protects buf1 tile (consumed P5)
    if (more) stage(A, m0 + 128, k2, A0c + 16384);
    if (it == 31) { asm volatile("s_waitcnt vmcnt(0)" ::: "memory"); }
    else          { asm volatile("s_waitcnt vmcnt(4)" ::: "memory"); }
    PH_SYNC_MFMA_BEGIN; MM(a1, b1, 4, 2); PH_END;
    // P5: reads buf1{A03,B01}; refill buf0.Bh0
    RD_A(a0, A1c, 0); RD_B(b0, B1c, 0);
    if (more) stage(Bt, n0, k2, B0c);
    PH_SYNC_MFMA_BEGIN; MM(a0, b0, 0, 0); PH_END;
    // P6: reads buf1{A47,B23}; refill buf0.Bh1
    RD_A(a1, A1c, 4); RD_B(b1, B1c, 2);
    if (more) stage(Bt, n0 + 128, k2, B0c + 16384);
    PH_SYNC_MFMA_BEGIN; MM(a0, b1, 0, 2); PH_END;
    // P7: buf1 fully consumed -> refill buf1.Ah0 (tile 2it+3)
    if (more) stage(A, m0, k3, A1c);
    PH_SYNC_MFMA_BEGIN; MM(a1, b0, 4, 0); PH_END;
    // P8: refill buf1.Ah1; counted vmcnt protects buf0 tile (consumed next P1)
    if (more) stage(A, m0 + 128, k3, A1c + 16384);
    asm volatile("s_waitcnt vmcnt(4)" ::: "memory");
    PH_SYNC_MFMA_BEGIN; MM(a1, b1, 4, 2); PH_END;
  }

  // ---- epilogue
#pragma unroll
  for (int m = 0; m < 8; ++m)
#pragma unroll
    for (int n = 0; n < 4; ++n)
#pragma unroll
      for (int i = 0; i < 4; ++i) {
        int row = m0 + wr * 128 + m * 16 + l4 * 4 + i;
        int col = n0 + wc * 64 + n * 16 + l15;
        C[(size_t)row * ldc + col] = (OUT_T)acc[m][n][i];
      }
}

// ---------------- flash-style causal GQA attention ----------------
__global__ __launch_bounds__(256) void attn_kernel(const bf16* __restrict__ QKV,
                                                   const bf16* __restrict__ Vt_g,
                                                   bf16* __restrict__ attn) {
  __shared__ __align__(16) bf16 Klds[64 * 128];   // [ks][d], XOR-swizzled (slot ^= row&7)
  __shared__ __align__(16) bf16 Vlds[128 * 64];   // [d][ks], XOR-swizzled (slot ^= row&7)
  __shared__ __align__(16) bf16 Plds[4 * 16 * 64];// per-wave [16 q][64 ks], XOR-swizzled
  const int bid = blockIdx.x;
  const int g = bid & 7;             // kv head
  const int slot_ = bid >> 3;
  const int h = g * 4 + (slot_ & 3); // q head
  const int qb = slot_ >> 2;
  const int q0 = qb * 64;
  const int tid = threadIdx.x, w = tid >> 6, lane = tid & 63;
  const int l15 = lane & 15, l4 = lane >> 4;
  const int wq0 = q0 + w * 16;
  const int qcol = h * 128;
  const int kcol = 4096 + g * 128;
  const float scale = 0.08838834764831845f;  // 1/sqrt(128)
  const float LOG2E = 1.4426950408889634f;

  bf16x8 aq[4];
#pragma unroll
  for (int kc = 0; kc < 4; ++kc)
    aq[kc] = *(const bf16x8*)(QKV + (size_t)(wq0 + l15) * QKVN + qcol + kc * 32 + l4 * 8);

  f32x4 acc_o[8] = {};
  float mrow[4], lrow[4];
#pragma unroll
  for (int i = 0; i < 4; ++i) { mrow[i] = -1e30f; lrow[i] = 0.f; }

  const bf16* Vhead = Vt_g + (size_t)g * 128 * SEQ;

  const int nkb = qb + 1;
  for (int kbi = 0; kbi < nkb; ++kbi) {
    int kb = kbi * 64;
#pragma unroll
    for (int p = 0; p < 4; ++p) {
      int ck = p * 256 + tid;
      int krow = ck >> 4, kslot = ck & 15;
      int ksl = kslot ^ (krow & 7);
      gload_lds16((const char*)(QKV + (size_t)(kb + krow) * QKVN + kcol) + ksl * 16,
                  (char*)Klds + ck * 16);
      int cv = p * 256 + tid;
      int vrow = cv >> 3, vslot = cv & 7;
      int vsl = vslot ^ (vrow & 7);
      gload_lds16(Vhead + (size_t)vrow * SEQ + kb + vsl * 8,
                  (char*)Vlds + cv * 16);
    }
    __syncthreads();
    f32x4 accs[4] = {};
#pragma unroll
    for (int n = 0; n < 4; ++n) {
      int row_ = n * 16 + l15;
      int sw = (row_ & 7) << 4;
#pragma unroll
      for (int kc = 0; kc < 4; ++kc) {
        bf16x8 bk = *(const bf16x8*)((const char*)Klds + row_ * 256 + ((kc * 64 + l4 * 16) ^ sw));
        accs[n] = __builtin_amdgcn_mfma_f32_16x16x32_bf16(aq[kc], bk, accs[n], 0, 0, 0);
      }
    }
    bool needmask = (kb + 64 > wq0);
    float s[4][4];
#pragma unroll
    for (int n = 0; n < 4; ++n)
#pragma unroll
      for (int i = 0; i < 4; ++i) {
        float v = accs[n][i] * scale;
        if (needmask) {
          int ks = kb + n * 16 + l15;
          int qr = wq0 + l4 * 4 + i;
          if (ks > qr) v = -1e30f;
        }
        s[n][i] = v;
      }
    float fac[4], ps[4][4];
#pragma unroll
    for (int i = 0; i < 4; ++i) {
      float t = fmaxf(fmaxf(s[0][i], s[1][i]), fmaxf(s[2][i], s[3][i]));
      t = fmaxf(t, __shfl_xor(t, 1));
      t = fmaxf(t, __shfl_xor(t, 2));
      t = fmaxf(t, __shfl_xor(t, 4));
      t = fmaxf(t, __shfl_xor(t, 8));
      float mnew = fmaxf(mrow[i], t);
      fac[i] = exp2f((mrow[i] - mnew) * LOG2E);
      float psum = 0.f;
#pragma unroll
      for (int n = 0; n < 4; ++n) {
        float p = exp2f((s[n][i] - mnew) * LOG2E);
        ps[n][i] = p; psum += p;
      }
      psum += __shfl_xor(psum, 1);
      psum += __shfl_xor(psum, 2);
      psum += __shfl_xor(psum, 4);
      psum += __shfl_xor(psum, 8);
      lrow[i] = lrow[i] * fac[i] + psum;
      mrow[i] = mnew;
    }
#pragma unroll
    for (int n2 = 0; n2 < 8; ++n2)
#pragma unroll
      for (int i = 0; i < 4; ++i)
        acc_o[n2][i] *= fac[i];
    char* Pw = (char*)Plds + w * 2048;
#pragma unroll
    for (int n = 0; n < 4; ++n)
#pragma unroll
      for (int i = 0; i < 4; ++i) {
        int r = l4 * 4 + i;
        int b = (r * 128 + (n * 16 + l15) * 2) ^ ((r & 7) << 4);
        *(bf16*)(Pw + b) = (bf16)ps[n][i];
      }
    __builtin_amdgcn_sched_barrier(0);
    asm volatile("" ::: "memory");
    bf16x8 pa[2];
#pragma unroll
    for (int kc = 0; kc < 2; ++kc)
      pa[kc] = *(const bf16x8*)(Pw + (l15 * 128 + ((kc * 64 + l4 * 16) ^ ((l15 & 7) << 4))));
#pragma unroll
    for (int n2 = 0; n2 < 8; ++n2) {
      int row_ = n2 * 16 + l15;
      int sw = (row_ & 7) << 4;
#pragma unroll
      for (int kc = 0; kc < 2; ++kc) {
        bf16x8 bv = *(const bf16x8*)((const char*)Vlds + row_ * 128 + ((kc * 64 + l4 * 16) ^ sw));
        acc_o[n2] = __builtin_amdgcn_mfma_f32_16x16x32_bf16(pa[kc], bv, acc_o[n2], 0, 0, 0);
      }
    }
    __syncthreads();
  }
#pragma unroll
  for (int n2 = 0; n2 < 8; ++n2)
#pragma unroll
    for (int i = 0; i < 4; ++i) {
      int row = wq0 + l4 * 4 + i;
      int col = h * 128 + n2 * 16 + l15;
      attn[(size_t)row * 4096 + col] = (bf16)(acc_o[n2][i] / lrow[i]);
    }
}

extern "C" void kernel_launch(void* const* d_in, const int* in_sizes, int n_in,
                              void* d_out, int out_size, void* d_ws, size_t ws_size,
                              hipStream_t stream) {
  const float* X  = (const float*)d_in[0];
  const float* Wq = (const float*)d_in[1];
  const float* Wk = (const float*)d_in[2];
  const float* Wv = (const float*)d_in[3];
  const float* Wo = (const float*)d_in[4];
  float* out = (float*)d_out;

  const size_t XB_OFF  = 0;
  const size_t WT_OFF  = 16777216;
  const size_t VT_OFF  = WT_OFF + 33554432;       // inside Wt region, past Wo^T
  const size_t QKV_OFF = 16777216 + 50331648;
  if (ws_size < (size_t)92274688) return;

  char* ws = (char*)d_ws;
  bf16* Xb    = (bf16*)(ws + XB_OFF);
  bf16* Wt    = (bf16*)(ws + WT_OFF);
  bf16* Vt_g  = (bf16*)(ws + VT_OFF);
  bf16* QKV   = (bf16*)(ws + QKV_OFF);
  bf16* attnb = Xb;  // reuse after gemm1 consumed Xb

  // 1. cast hidden states
  cast_f32_bf16<<<2048, 256, 0, stream>>>(X, Xb, SEQ * HID);
  // 2. transpose-cast Wq/Wk/Wv into fused [6144][4096] B^T
  transpose_cast<<<dim3(4096 / 32, 4096 / 32), 256, 0, stream>>>(Wq, Wt, 4096, 0);
  transpose_cast<<<dim3(1024 / 32, 4096 / 32), 256, 0, stream>>>(Wk, Wt, 1024, 4096);
  transpose_cast<<<dim3(1024 / 32, 4096 / 32), 256, 0, stream>>>(Wv, Wt, 1024, 5120);
  // 3. fused QKV projection: [2048,4096] @ [4096,6144], 8-phase 256^2
  gemm256<bf16><<<192, 512, 0, stream>>>(Xb, Wt, QKV, 24, QKVN);
  // 4. transpose-cast Wo (reuses Wt space) + transpose V into global [g][d][s]
  transpose_cast<<<dim3(4096 / 32, 4096 / 32), 256, 0, stream>>>(Wo, Wt, 4096, 0);
  transpose_v<<<dim3(SEQ / 32, 4, 8), 256, 0, stream>>>(QKV, Vt_g);
  // 5. causal GQA flash attention (balanced + XCD-aware 1-D grid)
  attn_kernel<<<1024, 256, 0, stream>>>(QKV, Vt_g, attnb);
  // 6. output projection -> f32 out: [2048,4096] @ [4096,4096], 8-phase 256^2
  gemm256<float><<<128, 512, 0, stream>>>(attnb, Wt, out, 16, 4096);
}

// Round 4
// 413.922 us; speedup vs baseline: 1.2681x; 1.2681x over previous
//
#include <hip/hip_runtime.h>
#include <hip/hip_bf16.h>

typedef __bf16 bf16;
typedef __bf16 bf16x4 __attribute__((ext_vector_type(4)));
typedef __bf16 bf16x8 __attribute__((ext_vector_type(8)));
typedef float  f32x4  __attribute__((ext_vector_type(4)));

#define SEQ  2048
#define HID  4096
#define QKVN 6144   // 4096 Q + 1024 K + 1024 V

__device__ __forceinline__ void gload_lds16(const void* g, void* l) {
  __builtin_amdgcn_global_load_lds(
      (const __attribute__((address_space(1))) void*)g,
      (__attribute__((address_space(3))) void*)l, 16, 0, 0);
}

// ---------------- cast f32 -> bf16 (vectorized) ----------------
__global__ __launch_bounds__(256) void cast_f32_bf16(const float* __restrict__ in,
                                                     bf16* __restrict__ out, int n) {
  int i = (blockIdx.x * 256 + threadIdx.x) * 4;
  int stride = gridDim.x * 256 * 4;
  for (; i < n; i += stride) {
    float4 v = *(const float4*)(in + i);
    bf16x4 o;
    o[0] = (bf16)v.x; o[1] = (bf16)v.y; o[2] = (bf16)v.z; o[3] = (bf16)v.w;
    *(bf16x4*)(out + i) = o;
  }
}

// ---------------- tiled transpose + cast: W[4096][N] f32 -> Wt[roff+N][4096] bf16 ----------------
__global__ __launch_bounds__(256) void transpose_cast(const float* __restrict__ W,
                                                      bf16* __restrict__ Wt,
                                                      int N, int roff) {
  __shared__ float tile[32][33];
  int k0 = blockIdx.y * 32;
  int n0 = blockIdx.x * 32;
  int t = threadIdx.x;
  int r = t >> 5, c = t & 31;
#pragma unroll
  for (int p = 0; p < 4; ++p)
    tile[r + p * 8][c] = W[(size_t)(k0 + r + p * 8) * N + n0 + c];
  __syncthreads();
#pragma unroll
  for (int p = 0; p < 4; ++p)
    Wt[(size_t)(roff + n0 + r + p * 8) * 4096 + k0 + c] = (bf16)tile[c][r + p * 8];
}

// ---------------- transpose V out of QKV into global: Vt_g[g][d][s] ----------------
__global__ __launch_bounds__(256) void transpose_v(const bf16* __restrict__ QKV,
                                                   bf16* __restrict__ Vt_g) {
  __shared__ bf16 tile[32][33];
  int s0 = blockIdx.x * 32;          // seq tile
  int d0 = blockIdx.y * 32;          // head-dim tile
  int g  = blockIdx.z;               // kv head
  int t = threadIdx.x;
  int r = t >> 5, c = t & 31;
#pragma unroll
  for (int p = 0; p < 4; ++p)
    tile[r + p * 8][c] = QKV[(size_t)(s0 + r + p * 8) * QKVN + 5120 + g * 128 + d0 + c];
  __syncthreads();
#pragma unroll
  for (int p = 0; p < 4; ++p)
    Vt_g[(size_t)(g * 128 + d0 + r + p * 8) * SEQ + s0 + c] = tile[c][r + p * 8];
}

// ---------------- m97-style 128x128 GEMM, A[M,K] @ Bt[N,K]^T -> C[M,ldc] ----------------
template <typename OUT_T>
__global__ __launch_bounds__(256) void gemm_bt(const bf16* __restrict__ A,
                                               const bf16* __restrict__ Bt,
                                               OUT_T* __restrict__ C,
                                               int K, int ldc) {
  __shared__ __align__(16) bf16 Abuf[128 * 32];
  __shared__ __align__(16) bf16 Bbuf[128 * 32];
  int m0 = blockIdx.y * 128, n0 = blockIdx.x * 128;
  int tid = threadIdx.x, w = tid >> 6, lane = tid & 63;
  int wr = w >> 1, wc = w & 1;
  int l15 = lane & 15, l4 = lane >> 4;
  f32x4 acc[4][4] = {};
  const int nk = K >> 5;
  for (int kt = 0; kt < nk; ++kt) {
    int k0 = kt << 5;
#pragma unroll
    for (int p = 0; p < 2; ++p) {
      int elem = p * 2048 + w * 512 + lane * 8;
      int row = elem >> 5, col = elem & 31;
      gload_lds16(A + (size_t)(m0 + row) * K + k0 + col, (char*)Abuf + 2 * elem);
      gload_lds16(Bt + (size_t)(n0 + row) * K + k0 + col, (char*)Bbuf + 2 * elem);
    }
    __syncthreads();
    bf16x8 af[4], bfr[4];
#pragma unroll
    for (int m = 0; m < 4; ++m)
      af[m] = *(const bf16x8*)(Abuf + (wr * 64 + m * 16 + l15) * 32 + l4 * 8);
#pragma unroll
    for (int n = 0; n < 4; ++n)
      bfr[n] = *(const bf16x8*)(Bbuf + (wc * 64 + n * 16 + l15) * 32 + l4 * 8);
#pragma unroll
    for (int m = 0; m < 4; ++m)
#pragma unroll
      for (int n = 0; n < 4; ++n)
        acc[m][n] = __builtin_amdgcn_mfma_f32_16x16x32_bf16(af[m], bfr[n], acc[m][n], 0, 0, 0);
    __syncthreads();
  }
#pragma unroll
  for (int m = 0; m < 4; ++m)
#pragma unroll
    for (int n = 0; n < 4; ++n)
#pragma unroll
      for (int i = 0; i < 4; ++i) {
        int row = m0 + wr * 64 + m * 16 + l4 * 4 + i;
        int col = n0 + wc * 64 + n * 16 + l15;
        C[(size_t)row * ldc + col] = (OUT_T)acc[m][n][i];
      }
}

// ---------------- flash-style causal GQA attention, v3 ----------------
// 256 blocks x 512 thr. Block = kv-head g (bid&7, XCD locality) x head-pair hg x qb-pair.
// Handles 2 q-heads (waves 0-3 / 4-7) x 2 q-blocks (qb_a = pair, qb_b = 31-pair) so every
// block runs exactly 33 K-tiles (perfect causal balance) and each staged K/V tile serves
// 2 heads (GQA sharing). K/V double-buffered: stage(t+1) issued before compute(t),
// one __syncthreads (vmcnt(0)+barrier) per tile (T3-minimum 2-phase).
__global__ __launch_bounds__(512, 2) void attn_kernel(const bf16* __restrict__ QKV,
                                                      const bf16* __restrict__ Vt_g,
                                                      bf16* __restrict__ attn) {
  __shared__ __align__(16) bf16 Klds[2][64 * 128];   // [ks][d], XOR-swizzled
  __shared__ __align__(16) bf16 Vlds[2][64 * 128];   // [d][ks], XOR-swizzled
  __shared__ __align__(16) bf16 Plds[8 * 16 * 64];   // per-wave [16 q][64 ks], swizzled
  const int bid = blockIdx.x;
  const int g = bid & 7;                 // kv head -> XCD
  const int rest = bid >> 3;             // 0..31
  const int hg = rest & 1;               // head pair within kv group
  const int pair = rest >> 1;            // 0..15
  const int qb_a = pair, qb_b = 31 - pair;
  const int tid = threadIdx.x, w = tid >> 6, lane = tid & 63;
  const int hsel = w >> 2, qw = w & 3;
  const int h = g * 4 + hg * 2 + hsel;   // this wave's q head
  const int l15 = lane & 15, l4 = lane >> 4;
  const int wqA = qb_a * 64 + qw * 16;   // wave's q-row base, block A
  const int wqB = qb_b * 64 + qw * 16;   // block B
  const int qcol = h * 128;
  const int kcol = 4096 + g * 128;
  const float scale = 0.08838834764831845f;  // 1/sqrt(128)
  const float LOG2E = 1.4426950408889634f;

  const bf16* Vhead = Vt_g + (size_t)g * 128 * SEQ;

  // hoist Q fragments for both q-blocks (16 rows x 128 d each)
  bf16x8 aqA[4], aqB[4];
#pragma unroll
  for (int kc = 0; kc < 4; ++kc) {
    aqA[kc] = *(const bf16x8*)(QKV + (size_t)(wqA + l15) * QKVN + qcol + kc * 32 + l4 * 8);
    aqB[kc] = *(const bf16x8*)(QKV + (size_t)(wqB + l15) * QKVN + qcol + kc * 32 + l4 * 8);
  }

  f32x4 acc_oA[8] = {}, acc_oB[8] = {};
  float mA[4], lA[4], mB[4], lB[4];
#pragma unroll
  for (int i = 0; i < 4; ++i) { mA[i] = -1e30f; lA[i] = 0.f; mB[i] = -1e30f; lB[i] = 0.f; }

  // stage K/V tile at k-offset kb into buffer buf (1024 16B-chunks each, 512 thr x 2)
  auto stageKV = [&](int kb, int buf) {
#pragma unroll
    for (int j = 0; j < 2; ++j) {
      int c = tid + (j << 9);
      int krow = c >> 4, kslot = c & 15;
      gload_lds16((const char*)(QKV + (size_t)(kb + krow) * QKVN + kcol) +
                      ((kslot ^ (krow & 7)) << 4),
                  (char*)Klds[buf] + c * 16);
      int vrow = c >> 3, vslot = c & 7;
      gload_lds16(Vhead + (size_t)vrow * SEQ + kb + ((vslot ^ (vrow & 7)) << 3),
                  (char*)Vlds[buf] + c * 16);
    }
  };

  // per-wave compute of one (head, q-block) unit against tile kb in buffer cur
  auto compute_block = [&](const bf16x8* aq, f32x4* acc_o, float* mrow, float* lrow,
                           int wq0, int kb, int cur) {
    const char* Kbuf = (const char*)Klds[cur];
    const char* Vbuf = (const char*)Vlds[cur];
    f32x4 accs[4] = {};
#pragma unroll
    for (int n = 0; n < 4; ++n) {
      int row_ = n * 16 + l15;
      int sw = (row_ & 7) << 4;
#pragma unroll
      for (int kc = 0; kc < 4; ++kc) {
        bf16x8 bk = *(const bf16x8*)(Kbuf + row_ * 256 + ((kc * 64 + l4 * 16) ^ sw));
        accs[n] = __builtin_amdgcn_mfma_f32_16x16x32_bf16(aq[kc], bk, accs[n], 0, 0, 0);
      }
    }
    bool needmask = (kb + 64 > wq0);
    float s[4][4];
#pragma unroll
    for (int n = 0; n < 4; ++n)
#pragma unroll
      for (int i = 0; i < 4; ++i) {
        float v = accs[n][i] * scale;
        if (needmask) {
          int ks = kb + n * 16 + l15;
          int qr = wq0 + l4 * 4 + i;
          if (ks > qr) v = -1e30f;
        }
        s[n][i] = v;
      }
    float fac[4], ps[4][4];
#pragma unroll
    for (int i = 0; i < 4; ++i) {
      float t = fmaxf(fmaxf(s[0][i], s[1][i]), fmaxf(s[2][i], s[3][i]));
      t = fmaxf(t, __shfl_xor(t, 1));
      t = fmaxf(t, __shfl_xor(t, 2));
      t = fmaxf(t, __shfl_xor(t, 4));
      t = fmaxf(t, __shfl_xor(t, 8));
      float mnew = fmaxf(mrow[i], t);
      fac[i] = exp2f((mrow[i] - mnew) * LOG2E);
      float psum = 0.f;
#pragma unroll
      for (int n = 0; n < 4; ++n) {
        float p = exp2f((s[n][i] - mnew) * LOG2E);
        ps[n][i] = p; psum += p;
      }
      psum += __shfl_xor(psum, 1);
      psum += __shfl_xor(psum, 2);
      psum += __shfl_xor(psum, 4);
      psum += __shfl_xor(psum, 8);
      lrow[i] = lrow[i] * fac[i] + psum;
      mrow[i] = mnew;
    }
#pragma unroll
    for (int n2 = 0; n2 < 8; ++n2)
#pragma unroll
      for (int i = 0; i < 4; ++i)
        acc_o[n2][i] *= fac[i];
    // P write (per-wave region, swizzled) then PV; DS ops are in-order per wave
    char* Pw = (char*)Plds + w * 2048;
#pragma unroll
    for (int n = 0; n < 4; ++n)
#pragma unroll
      for (int i = 0; i < 4; ++i) {
        int r = l4 * 4 + i;
        int b = (r * 128 + (n * 16 + l15) * 2) ^ ((r & 7) << 4);
        *(bf16*)(Pw + b) = (bf16)ps[n][i];
      }
    __builtin_amdgcn_sched_barrier(0);
    asm volatile("" ::: "memory");
    bf16x8 pa[2];
#pragma unroll
    for (int kc = 0; kc < 2; ++kc)
      pa[kc] = *(const bf16x8*)(Pw + (l15 * 128 + ((kc * 64 + l4 * 16) ^ ((l15 & 7) << 4))));
#pragma unroll
    for (int n2 = 0; n2 < 8; ++n2) {
      int row_ = n2 * 16 + l15;
      int sw = (row_ & 7) << 4;
#pragma unroll
      for (int kc = 0; kc < 2; ++kc) {
        bf16x8 bv = *(const bf16x8*)(Vbuf + row_ * 128 + ((kc * 64 + l4 * 16) ^ sw));
        acc_o[n2] = __builtin_amdgcn_mfma_f32_16x16x32_bf16(pa[kc], bv, acc_o[n2], 0, 0, 0);
      }
    }
    asm volatile("" ::: "memory");
  };

  // ---- prologue: stage tile 0; drain; ----
  stageKV(0, 0);
  __syncthreads();

  int cur = 0;
  for (int kbi = 0; kbi <= qb_b; ++kbi) {
    int kb = kbi * 64;
    if (kbi < qb_b) stageKV(kb + 64, cur ^ 1);        // issue-early (overlaps compute)
    if (kbi <= qb_a) compute_block(aqA, acc_oA, mA, lA, wqA, kb, cur);
    compute_block(aqB, acc_oB, mB, lB, wqB, kb, cur);
    __syncthreads();                                   // vmcnt(0)+barrier per tile
    cur ^= 1;
  }

  // ---- epilogue ----
#pragma unroll
  for (int n2 = 0; n2 < 8; ++n2)
#pragma unroll
    for (int i = 0; i < 4; ++i) {
      int col = qcol + n2 * 16 + l15;
      attn[(size_t)(wqA + l4 * 4 + i) * 4096 + col] = (bf16)(acc_oA[n2][i] / lA[i]);
      attn[(size_t)(wqB + l4 * 4 + i) * 4096 + col] = (bf16)(acc_oB[n2][i] / lB[i]);
    }
}

extern "C" void kernel_launch(void* const* d_in, const int* in_sizes, int n_in,
                              void* d_out, int out_size, void* d_ws, size_t ws_size,
                              hipStream_t stream) {
  const float* X  = (const float*)d_in[0];
  const float* Wq = (const float*)d_in[1];
  const float* Wk = (const float*)d_in[2];
  const float* Wv = (const float*)d_in[3];
  const float* Wo = (const float*)d_in[4];
  float* out = (float*)d_out;

  const size_t XB_OFF  = 0;
  const size_t WT_OFF  = 16777216;
  const size_t VT_OFF  = WT_OFF + 33554432;       // inside Wt region, past Wo^T
  const size_t QKV_OFF = 16777216 + 50331648;
  if (ws_size < (size_t)92274688) return;

  char* ws = (char*)d_ws;
  bf16* Xb    = (bf16*)(ws + XB_OFF);
  bf16* Wt    = (bf16*)(ws + WT_OFF);
  bf16* Vt_g  = (bf16*)(ws + VT_OFF);
  bf16* QKV   = (bf16*)(ws + QKV_OFF);
  bf16* attnb = Xb;  // reuse after gemm1 consumed Xb

  // 1. cast hidden states
  cast_f32_bf16<<<2048, 256, 0, stream>>>(X, Xb, SEQ * HID);
  // 2. transpose-cast Wq/Wk/Wv into fused [6144][4096] B^T
  transpose_cast<<<dim3(4096 / 32, 4096 / 32), 256, 0, stream>>>(Wq, Wt, 4096, 0);
  transpose_cast<<<dim3(1024 / 32, 4096 / 32), 256, 0, stream>>>(Wk, Wt, 1024, 4096);
  transpose_cast<<<dim3(1024 / 32, 4096 / 32), 256, 0, stream>>>(Wv, Wt, 1024, 5120);
  // 3. fused QKV projection: [2048,4096] @ [4096,6144]
  gemm_bt<bf16><<<dim3(QKVN / 128, SEQ / 128), 256, 0, stream>>>(Xb, Wt, QKV, HID, QKVN);
  // 4. transpose-cast Wo (reuses Wt space) + transpose V into global [g][d][s]
  transpose_cast<<<dim3(4096 / 32, 4096 / 32), 256, 0, stream>>>(Wo, Wt, 4096, 0);
  transpose_v<<<dim3(SEQ / 32, 4, 8), 256, 0, stream>>>(QKV, Vt_g);
  // 5. causal GQA flash attention v3 (balanced pairs, GQA-shared staging, 2-phase dbuf)
  attn_kernel<<<256, 512, 0, stream>>>(QKV, Vt_g, attnb);
  // 6. output projection -> f32 out: [2048,4096] @ [4096,4096]
  gemm_bt<float><<<dim3(4096 / 128, SEQ / 128), 256, 0, stream>>>(attnb, Wt, out, HID, 4096);
}

// Round 5
// 378.959 us; speedup vs baseline: 1.3851x; 1.0923x over previous
//
#include <hip/hip_runtime.h>
#include <hip/hip_bf16.h>

typedef __bf16 bf16;
typedef __bf16 bf16x4 __attribute__((ext_vector_type(4)));
typedef __bf16 bf16x8 __attribute__((ext_vector_type(8)));
typedef float  f32x4  __attribute__((ext_vector_type(4)));

#define SEQ  2048
#define HID  4096
#define QKVN 6144   // 4096 Q + 1024 K + 1024 V

__device__ __forceinline__ void gload_lds16(const void* g, void* l) {
  __builtin_amdgcn_global_load_lds(
      (const __attribute__((address_space(1))) void*)g,
      (__attribute__((address_space(3))) void*)l, 16, 0, 0);
}

// ---------------- cast f32 -> bf16 (vectorized) ----------------
__global__ __launch_bounds__(256) void cast_f32_bf16(const float* __restrict__ in,
                                                     bf16* __restrict__ out, int n) {
  int i = (blockIdx.x * 256 + threadIdx.x) * 4;
  int stride = gridDim.x * 256 * 4;
  for (; i < n; i += stride) {
    float4 v = *(const float4*)(in + i);
    bf16x4 o;
    o[0] = (bf16)v.x; o[1] = (bf16)v.y; o[2] = (bf16)v.z; o[3] = (bf16)v.w;
    *(bf16x4*)(out + i) = o;
  }
}

// ---------------- tiled transpose + cast: W[4096][N] f32 -> Wt[roff+N][4096] bf16 ----------------
__global__ __launch_bounds__(256) void transpose_cast(const float* __restrict__ W,
                                                      bf16* __restrict__ Wt,
                                                      int N, int roff) {
  __shared__ float tile[32][33];
  int k0 = blockIdx.y * 32;
  int n0 = blockIdx.x * 32;
  int t = threadIdx.x;
  int r = t >> 5, c = t & 31;
#pragma unroll
  for (int p = 0; p < 4; ++p)
    tile[r + p * 8][c] = W[(size_t)(k0 + r + p * 8) * N + n0 + c];
  __syncthreads();
#pragma unroll
  for (int p = 0; p < 4; ++p)
    Wt[(size_t)(roff + n0 + r + p * 8) * 4096 + k0 + c] = (bf16)tile[c][r + p * 8];
}

// ---------------- transpose V out of QKV into global: Vt_g[g][d][s] ----------------
__global__ __launch_bounds__(256) void transpose_v(const bf16* __restrict__ QKV,
                                                   bf16* __restrict__ Vt_g) {
  __shared__ bf16 tile[32][33];
  int s0 = blockIdx.x * 32;          // seq tile
  int d0 = blockIdx.y * 32;          // head-dim tile
  int g  = blockIdx.z;               // kv head
  int t = threadIdx.x;
  int r = t >> 5, c = t & 31;
#pragma unroll
  for (int p = 0; p < 4; ++p)
    tile[r + p * 8][c] = QKV[(size_t)(s0 + r + p * 8) * QKVN + 5120 + g * 128 + d0 + c];
  __syncthreads();
#pragma unroll
  for (int p = 0; p < 4; ++p)
    Vt_g[(size_t)(g * 128 + d0 + r + p * 8) * SEQ + s0 + c] = tile[c][r + p * 8];
}

// ---------------- 128x128 GEMM, BK=64, swizzled LDS: A[M,K] @ Bt[N,K]^T -> C[M,ldc] ----------------
// vs m97-structure BK=32: barrier count halved (64 iters for K=4096), per-iter 8 gload +
// 16 ds_read_b128 + 32 MFMA. LDS tiles XOR-swizzled (slot ^= row&7, 16B slots) via
// pre-swizzled global source + swizzled fragment read (both-sides rule) -> 2-way bank
// aliasing (free) instead of the BK=32 layout's measured 1.26e7 conflicts.
template <typename OUT_T>
__global__ __launch_bounds__(256) void gemm_bt(const bf16* __restrict__ A,
                                               const bf16* __restrict__ Bt,
                                               OUT_T* __restrict__ C,
                                               int K, int ldc) {
  __shared__ __align__(16) bf16 Abuf[128 * 64];
  __shared__ __align__(16) bf16 Bbuf[128 * 64];
  int m0 = blockIdx.y * 128, n0 = blockIdx.x * 128;
  int tid = threadIdx.x, w = tid >> 6, lane = tid & 63;
  int wr = w >> 1, wc = w & 1;
  int l15 = lane & 15, l4 = lane >> 4;
  f32x4 acc[4][4] = {};
  const int nk = K >> 6;
  for (int kt = 0; kt < nk; ++kt) {
    int k0 = kt << 6;
    // stage A,B tiles (128 rows x 64 cols bf16 = 16KB each = 1024 16B-chunks; 4/thread)
#pragma unroll
    for (int p = 0; p < 4; ++p) {
      int c = p * 256 + tid;
      int row = c >> 3, slot = c & 7;
      int ssl = (slot ^ (row & 7)) << 4;   // inverse-swizzled source byte offset
      gload_lds16((const char*)(A + (size_t)(m0 + row) * K + k0) + ssl, (char*)Abuf + c * 16);
      gload_lds16((const char*)(Bt + (size_t)(n0 + row) * K + k0) + ssl, (char*)Bbuf + c * 16);
    }
    __syncthreads();
    bf16x8 af[4][2], bfr[4][2];
#pragma unroll
    for (int m = 0; m < 4; ++m)
#pragma unroll
      for (int kk = 0; kk < 2; ++kk) {
        int row = wr * 64 + m * 16 + l15;
        af[m][kk] = *(const bf16x8*)((const char*)Abuf + row * 128 +
                                     (((kk * 4 + l4) ^ (row & 7)) << 4));
      }
#pragma unroll
    for (int n = 0; n < 4; ++n)
#pragma unroll
      for (int kk = 0; kk < 2; ++kk) {
        int row = wc * 64 + n * 16 + l15;
        bfr[n][kk] = *(const bf16x8*)((const char*)Bbuf + row * 128 +
                                      (((kk * 4 + l4) ^ (row & 7)) << 4));
      }
#pragma unroll
    for (int kk = 0; kk < 2; ++kk)
#pragma unroll
      for (int m = 0; m < 4; ++m)
#pragma unroll
        for (int n = 0; n < 4; ++n)
          acc[m][n] = __builtin_amdgcn_mfma_f32_16x16x32_bf16(af[m][kk], bfr[n][kk],
                                                              acc[m][n], 0, 0, 0);
    __syncthreads();
  }
#pragma unroll
  for (int m = 0; m < 4; ++m)
#pragma unroll
    for (int n = 0; n < 4; ++n)
#pragma unroll
      for (int i = 0; i < 4; ++i) {
        int row = m0 + wr * 64 + m * 16 + l4 * 4 + i;
        int col = n0 + wc * 64 + n * 16 + l15;
        C[(size_t)row * ldc + col] = (OUT_T)acc[m][n][i];
      }
}

// ---------------- flash-style causal GQA attention, v3 + T5/T13 ----------------
// 256 blocks x 512 thr. Block = kv-head g (bid&7, XCD locality) x head-pair hg x qb-pair.
// 2 q-heads (waves 0-3 / 4-7) x 2 q-blocks (qb_a = pair, qb_b = 31-pair): every block runs
// exactly 33 K-tiles; each staged K/V tile serves 2 heads. K/V double-buffered, stage(t+1)
// issued before compute(t), one __syncthreads per tile. setprio around MFMA clusters (T5),
// defer-max rescale threshold 8 (T13).
__global__ __launch_bounds__(512, 2) void attn_kernel(const bf16* __restrict__ QKV,
                                                      const bf16* __restrict__ Vt_g,
                                                      bf16* __restrict__ attn) {
  __shared__ __align__(16) bf16 Klds[2][64 * 128];   // [ks][d], XOR-swizzled
  __shared__ __align__(16) bf16 Vlds[2][64 * 128];   // [d][ks], XOR-swizzled
  __shared__ __align__(16) bf16 Plds[8 * 16 * 64];   // per-wave [16 q][64 ks], swizzled
  const int bid = blockIdx.x;
  const int g = bid & 7;                 // kv head -> XCD
  const int rest = bid >> 3;             // 0..31
  const int hg = rest & 1;               // head pair within kv group
  const int pair = rest >> 1;            // 0..15
  const int qb_a = pair, qb_b = 31 - pair;
  const int tid = threadIdx.x, w = tid >> 6, lane = tid & 63;
  const int hsel = w >> 2, qw = w & 3;
  const int h = g * 4 + hg * 2 + hsel;   // this wave's q head
  const int l15 = lane & 15, l4 = lane >> 4;
  const int wqA = qb_a * 64 + qw * 16;   // wave's q-row base, block A
  const int wqB = qb_b * 64 + qw * 16;   // block B
  const int qcol = h * 128;
  const int kcol = 4096 + g * 128;
  const float scale = 0.08838834764831845f;  // 1/sqrt(128)
  const float LOG2E = 1.4426950408889634f;

  const bf16* Vhead = Vt_g + (size_t)g * 128 * SEQ;

  // hoist Q fragments for both q-blocks (16 rows x 128 d each)
  bf16x8 aqA[4], aqB[4];
#pragma unroll
  for (int kc = 0; kc < 4; ++kc) {
    aqA[kc] = *(const bf16x8*)(QKV + (size_t)(wqA + l15) * QKVN + qcol + kc * 32 + l4 * 8);
    aqB[kc] = *(const bf16x8*)(QKV + (size_t)(wqB + l15) * QKVN + qcol + kc * 32 + l4 * 8);
  }

  f32x4 acc_oA[8] = {}, acc_oB[8] = {};
  float mA[4], lA[4], mB[4], lB[4];
#pragma unroll
  for (int i = 0; i < 4; ++i) { mA[i] = -1e30f; lA[i] = 0.f; mB[i] = -1e30f; lB[i] = 0.f; }

  // stage K/V tile at k-offset kb into buffer buf (1024 16B-chunks each, 512 thr x 2)
  auto stageKV = [&](int kb, int buf) {
#pragma unroll
    for (int j = 0; j < 2; ++j) {
      int c = tid + (j << 9);
      int krow = c >> 4, kslot = c & 15;
      gload_lds16((const char*)(QKV + (size_t)(kb + krow) * QKVN + kcol) +
                      ((kslot ^ (krow & 7)) << 4),
                  (char*)Klds[buf] + c * 16);
      int vrow = c >> 3, vslot = c & 7;
      gload_lds16(Vhead + (size_t)vrow * SEQ + kb + ((vslot ^ (vrow & 7)) << 3),
                  (char*)Vlds[buf] + c * 16);
    }
  };

  // per-wave compute of one (head, q-block) unit against tile kb in buffer cur
  auto compute_block = [&](const bf16x8* aq, f32x4* acc_o, float* mrow, float* lrow,
                           int wq0, int kb, int cur) {
    const char* Kbuf = (const char*)Klds[cur];
    const char* Vbuf = (const char*)Vlds[cur];
    f32x4 accs[4] = {};
    __builtin_amdgcn_s_setprio(1);
#pragma unroll
    for (int n = 0; n < 4; ++n) {
      int row_ = n * 16 + l15;
      int sw = (row_ & 7) << 4;
#pragma unroll
      for (int kc = 0; kc < 4; ++kc) {
        bf16x8 bk = *(const bf16x8*)(Kbuf + row_ * 256 + ((kc * 64 + l4 * 16) ^ sw));
        accs[n] = __builtin_amdgcn_mfma_f32_16x16x32_bf16(aq[kc], bk, accs[n], 0, 0, 0);
      }
    }
    __builtin_amdgcn_s_setprio(0);
    bool needmask = (kb + 64 > wq0);
    float s[4][4];
#pragma unroll
    for (int n = 0; n < 4; ++n)
#pragma unroll
      for (int i = 0; i < 4; ++i) {
        float v = accs[n][i] * scale;
        if (needmask) {
          int ks = kb + n * 16 + l15;
          int qr = wq0 + l4 * 4 + i;
          if (ks > qr) v = -1e30f;
        }
        s[n][i] = v;
      }
    // ---- row max (t4) + defer-max decision (T13) ----
    float t4[4];
#pragma unroll
    for (int i = 0; i < 4; ++i) {
      float t = fmaxf(fmaxf(s[0][i], s[1][i]), fmaxf(s[2][i], s[3][i]));
      t = fmaxf(t, __shfl_xor(t, 1));
      t = fmaxf(t, __shfl_xor(t, 2));
      t = fmaxf(t, __shfl_xor(t, 4));
      t = fmaxf(t, __shfl_xor(t, 8));
      t4[i] = t;
    }
    float dm = fmaxf(fmaxf(t4[0] - mrow[0], t4[1] - mrow[1]),
                     fmaxf(t4[2] - mrow[2], t4[3] - mrow[3]));
    if (!__all(dm <= 8.0f)) {
      float fac[4];
#pragma unroll
      for (int i = 0; i < 4; ++i) {
        float mnew = fmaxf(mrow[i], t4[i]);
        fac[i] = exp2f((mrow[i] - mnew) * LOG2E);
        mrow[i] = mnew;
        lrow[i] *= fac[i];
      }
#pragma unroll
      for (int n2 = 0; n2 < 8; ++n2)
#pragma unroll
        for (int i = 0; i < 4; ++i)
          acc_o[n2][i] *= fac[i];
    }
    // ---- P = exp(s - m), row-sum into l ----
    float ps[4][4];
#pragma unroll
    for (int i = 0; i < 4; ++i) {
      float psum = 0.f;
#pragma unroll
      for (int n = 0; n < 4; ++n) {
        float p = exp2f((s[n][i] - mrow[i]) * LOG2E);
        ps[n][i] = p; psum += p;
      }
      psum += __shfl_xor(psum, 1);
      psum += __shfl_xor(psum, 2);
      psum += __shfl_xor(psum, 4);
      psum += __shfl_xor(psum, 8);
      lrow[i] += psum;
    }
    // P write (per-wave region, swizzled) then PV; DS ops are in-order per wave
    char* Pw = (char*)Plds + w * 2048;
#pragma unroll
    for (int n = 0; n < 4; ++n)
#pragma unroll
      for (int i = 0; i < 4; ++i) {
        int r = l4 * 4 + i;
        int b = (r * 128 + (n * 16 + l15) * 2) ^ ((r & 7) << 4);
        *(bf16*)(Pw + b) = (bf16)ps[n][i];
      }
    __builtin_amdgcn_sched_barrier(0);
    asm volatile("" ::: "memory");
    bf16x8 pa[2];
#pragma unroll
    for (int kc = 0; kc < 2; ++kc)
      pa[kc] = *(const bf16x8*)(Pw + (l15 * 128 + ((kc * 64 + l4 * 16) ^ ((l15 & 7) << 4))));
    __builtin_amdgcn_s_setprio(1);
#pragma unroll
    for (int n2 = 0; n2 < 8; ++n2) {
      int row_ = n2 * 16 + l15;
      int sw = (row_ & 7) << 4;
#pragma unroll
      for (int kc = 0; kc < 2; ++kc) {
        bf16x8 bv = *(const bf16x8*)(Vbuf + row_ * 128 + ((kc * 64 + l4 * 16) ^ sw));
        acc_o[n2] = __builtin_amdgcn_mfma_f32_16x16x32_bf16(pa[kc], bv, acc_o[n2], 0, 0, 0);
      }
    }
    __builtin_amdgcn_s_setprio(0);
    asm volatile("" ::: "memory");
  };

  // ---- prologue: stage tile 0; drain; ----
  stageKV(0, 0);
  __syncthreads();

  int cur = 0;
  for (int kbi = 0; kbi <= qb_b; ++kbi) {
    int kb = kbi * 64;
    if (kbi < qb_b) stageKV(kb + 64, cur ^ 1);        // issue-early (overlaps compute)
    if (kbi <= qb_a) compute_block(aqA, acc_oA, mA, lA, wqA, kb, cur);
    compute_block(aqB, acc_oB, mB, lB, wqB, kb, cur);
    __syncthreads();                                   // vmcnt(0)+barrier per tile
    cur ^= 1;
  }

  // ---- epilogue ----
#pragma unroll
  for (int n2 = 0; n2 < 8; ++n2)
#pragma unroll
    for (int i = 0; i < 4; ++i) {
      int col = qcol + n2 * 16 + l15;
      attn[(size_t)(wqA + l4 * 4 + i) * 4096 + col] = (bf16)(acc_oA[n2][i] / lA[i]);
      attn[(size_t)(wqB + l4 * 4 + i) * 4096 + col] = (bf16)(acc_oB[n2][i] / lB[i]);
    }
}

extern "C" void kernel_launch(void* const* d_in, const int* in_sizes, int n_in,
                              void* d_out, int out_size, void* d_ws, size_t ws_size,
                              hipStream_t stream) {
  const float* X  = (const float*)d_in[0];
  const float* Wq = (const float*)d_in[1];
  const float* Wk = (const float*)d_in[2];
  const float* Wv = (const float*)d_in[3];
  const float* Wo = (const float*)d_in[4];
  float* out = (float*)d_out;

  const size_t XB_OFF  = 0;
  const size_t WT_OFF  = 16777216;
  const size_t VT_OFF  = WT_OFF + 33554432;       // inside Wt region, past Wo^T
  const size_t QKV_OFF = 16777216 + 50331648;
  if (ws_size < (size_t)92274688) return;

  char* ws = (char*)d_ws;
  bf16* Xb    = (bf16*)(ws + XB_OFF);
  bf16* Wt    = (bf16*)(ws + WT_OFF);
  bf16* Vt_g  = (bf16*)(ws + VT_OFF);
  bf16* QKV   = (bf16*)(ws + QKV_OFF);
  bf16* attnb = Xb;  // reuse after gemm1 consumed Xb

  // 1. cast hidden states
  cast_f32_bf16<<<2048, 256, 0, stream>>>(X, Xb, SEQ * HID);
  // 2. transpose-cast Wq/Wk/Wv into fused [6144][4096] B^T
  transpose_cast<<<dim3(4096 / 32, 4096 / 32), 256, 0, stream>>>(Wq, Wt, 4096, 0);
  transpose_cast<<<dim3(1024 / 32, 4096 / 32), 256, 0, stream>>>(Wk, Wt, 1024, 4096);
  transpose_cast<<<dim3(1024 / 32, 4096 / 32), 256, 0, stream>>>(Wv, Wt, 1024, 5120);
  // 3. fused QKV projection: [2048,4096] @ [4096,6144]
  gemm_bt<bf16><<<dim3(QKVN / 128, SEQ / 128), 256, 0, stream>>>(Xb, Wt, QKV, HID, QKVN);
  // 4. transpose-cast Wo (reuses Wt space) + transpose V into global [g][d][s]
  transpose_cast<<<dim3(4096 / 32, 4096 / 32), 256, 0, stream>>>(Wo, Wt, 4096, 0);
  transpose_v<<<dim3(SEQ / 32, 4, 8), 256, 0, stream>>>(QKV, Vt_g);
  // 5. causal GQA flash attention v3 (+T5 setprio, +T13 defer-max)
  attn_kernel<<<256, 512, 0, stream>>>(QKV, Vt_g, attnb);
  // 6. output projection -> f32 out: [2048,4096] @ [4096,4096]
  gemm_bt<float><<<dim3(4096 / 128, SEQ / 128), 256, 0, stream>>>(attnb, Wt, out, HID, 4096);
}